// Round 4
// baseline (499.271 us; speedup 1.0000x reference)
//
#include <hip/hip_runtime.h>
#include <hip/hip_bf16.h>
#include <math.h>

typedef short bf16x8 __attribute__((ext_vector_type(8)));
typedef float f32x4 __attribute__((ext_vector_type(4)));
typedef unsigned short u16;

__device__ inline u16 f2b(float f) {
    unsigned int u;
    __builtin_memcpy(&u, &f, 4);
    unsigned int lsb = (u >> 16) & 1u;
    u += 0x7fffu + lsb;
    return (u16)(u >> 16);
}

// ---------------------------------------------------------------------------
// Kernel 1: TF-style AveragePooling2D(3x3, stride 2, SAME), divide by valid
// count. x: (4,64,64,512) f32 -> xp: (4,32,32,512) bf16.
// pad_lo = 0, pad_hi = 1: output i covers input rows [2i, min(2i+3, 64)).
// ---------------------------------------------------------------------------
__global__ __launch_bounds__(256) void pool_kernel(const float* __restrict__ x,
                                                   u16* __restrict__ xp) {
    int idx = blockIdx.x * 256 + threadIdx.x;   // 2,097,152 total
    int c = idx & 511;
    int j = (idx >> 9) & 31;
    int i = (idx >> 14) & 31;
    int b = idx >> 19;
    int r0 = 2 * i, c0 = 2 * j;
    int rmax = min(r0 + 3, 64), cmax = min(c0 + 3, 64);
    float s = 0.f;
    for (int r = r0; r < rmax; ++r)
        for (int cc = c0; cc < cmax; ++cc)
            s += x[(((b << 6) + r) * 64 + cc) * 512 + c];
    int cnt = (rmax - r0) * (cmax - c0);
    xp[idx] = f2b(s / (float)cnt);
}

// ---------------------------------------------------------------------------
// Kernel 2: C(Mx512) = A(Mx512) @ W(512x512) + bias (+ residual)
// A: f32 (AT=float) or bf16-packed u16 (AT=u16). W/bias/res: f32.
// Output OT: u16 (bf16 intermediate) or float (final output).
// fp32 accumulate via mfma_f32_16x16x32_bf16.
// Block: 256 threads = 4 waves; tile 64(M) x 64(N); K step 32.
// MFMA layouts (HW-verified): A frag: m = lane&15, k = (lane>>4)*8+j.
// B frag: (k, n) with n = lane&15, k = (lane>>4)*8+j. C/D: col = lane&15,
// row = (lane>>4)*4 + reg.
// ---------------------------------------------------------------------------
template <bool RES, typename AT, typename OT>
__global__ __launch_bounds__(256) void gemm512(const AT* __restrict__ A,
                                               const float* __restrict__ W,
                                               const float* __restrict__ bias,
                                               const float* __restrict__ res,
                                               OT* __restrict__ C) {
    __shared__ __align__(16) u16 At[64 * 32];   // At[m][k]
    __shared__ __align__(16) u16 Wt[64 * 32];   // Wt[n][k]  (W transposed)
    int tid = threadIdx.x;
    int lane = tid & 63, wave = tid >> 6;
    int q = lane >> 4, l16 = lane & 15;
    int nBase = blockIdx.x * 64;
    int mBase = blockIdx.y * 64;
    f32x4 acc[4] = {};

    for (int kk = 0; kk < 512; kk += 32) {
        __syncthreads();
        if constexpr (sizeof(AT) == 4) {
            // A f32: 64x32 tile = 512 float4 chunks, 2 per thread
#pragma unroll
            for (int t2 = 0; t2 < 2; ++t2) {
                int e = tid + t2 * 256;
                int r = e >> 3, c4 = (e & 7) * 4;
                float4 v = *(const float4*)(&A[(size_t)(mBase + r) * 512 + kk + c4]);
                u16* dst = &At[r * 32 + c4];
                dst[0] = f2b(v.x); dst[1] = f2b(v.y);
                dst[2] = f2b(v.z); dst[3] = f2b(v.w);
            }
        } else {
            // A bf16: one 16B load per thread
            int r = tid >> 2, cc = (tid & 3) * 8;
            *(int4*)(&At[r * 32 + cc]) =
                *(const int4*)(&A[(size_t)(mBase + r) * 512 + kk + cc]);
        }
        {   // W f32: 32(k) x 64(n) tile, scatter transposed into Wt[n][k]
#pragma unroll
            for (int t2 = 0; t2 < 2; ++t2) {
                int e = tid + t2 * 256;
                int k = e >> 4, n4 = (e & 15) * 4;
                float4 v = *(const float4*)(&W[(size_t)(kk + k) * 512 + nBase + n4]);
                Wt[(n4 + 0) * 32 + k] = f2b(v.x);
                Wt[(n4 + 1) * 32 + k] = f2b(v.y);
                Wt[(n4 + 2) * 32 + k] = f2b(v.z);
                Wt[(n4 + 3) * 32 + k] = f2b(v.w);
            }
        }
        __syncthreads();
        bf16x8 a = *(bf16x8*)(&At[(wave * 16 + l16) * 32 + q * 8]);
#pragma unroll
        for (int cb = 0; cb < 4; ++cb) {
            bf16x8 b = *(bf16x8*)(&Wt[(cb * 16 + l16) * 32 + q * 8]);
            acc[cb] = __builtin_amdgcn_mfma_f32_16x16x32_bf16(a, b, acc[cb], 0, 0, 0);
        }
    }

#pragma unroll
    for (int cb = 0; cb < 4; ++cb) {
        int col = nBase + cb * 16 + l16;
        float bv = bias[col];
#pragma unroll
        for (int r = 0; r < 4; ++r) {
            int row = mBase + wave * 16 + q * 4 + r;
            float v = acc[cb][r] + bv;
            if (RES) v += res[(size_t)row * 512 + col];
            if constexpr (sizeof(OT) == 4) {
                C[(size_t)row * 512 + col] = v;
            } else {
                C[(size_t)row * 512 + col] = f2b(v);
            }
        }
    }
}

// ---------------------------------------------------------------------------
// Kernel 3: flash-style attention per group (flat-reshape semantics: group g
// is the contiguous block). Qg = (4096,64), Kg/Vg = (1024,64), bf16 in ws.
// S = Q K^T / 8, online softmax, O = P V.
// Block = 64 Q rows (4 waves x 16), loop over 16 KV tiles of 64.
// ---------------------------------------------------------------------------
__global__ __launch_bounds__(256) void attn_kernel(const u16* __restrict__ Q,
                                                   const u16* __restrict__ K,
                                                   const u16* __restrict__ V,
                                                   u16* __restrict__ O) {
    int g = blockIdx.y;
    int qtile = blockIdx.x;   // 0..63
    const u16* Qg = Q + (size_t)g * 262144;
    const u16* Kg = K + (size_t)g * 65536;
    const u16* Vg = V + (size_t)g * 65536;
    u16* Og = O + (size_t)g * 262144;

    __shared__ __align__(16) u16 Kt[64 * 64];   // Kt[m][d]
    __shared__ __align__(16) u16 VT[64 * 64];   // VT[d][m]
    __shared__ __align__(16) u16 Pt[64 * 64];   // Pt[n][m]

    int tid = threadIdx.x, lane = tid & 63, wave = tid >> 6;
    int q = lane >> 4, l16 = lane & 15;
    int n0 = qtile * 64;

    bf16x8 qf[2];
#pragma unroll
    for (int ds = 0; ds < 2; ++ds)
        qf[ds] = *(const bf16x8*)(&Qg[(size_t)(n0 + wave * 16 + l16) * 64 + ds * 32 + q * 8]);

    f32x4 oacc[4] = {};
    float m_i[4], l_i[4];
#pragma unroll
    for (int r = 0; r < 4; ++r) { m_i[r] = -INFINITY; l_i[r] = 0.f; }

    for (int kb = 0; kb < 16; ++kb) {
        __syncthreads();
#pragma unroll
        for (int t = 0; t < 2; ++t) {
            int e = tid + t * 256;          // 512 chunks of 8 elems
            int r = e >> 3, cc = (e & 7) * 8;
            *(int4*)(&Kt[r * 64 + cc]) =
                *(const int4*)(&Kg[(size_t)(kb * 64 + r) * 64 + cc]);
            int4 v = *(const int4*)(&Vg[(size_t)(kb * 64 + r) * 64 + cc]);
            const u16* pv = (const u16*)&v;
#pragma unroll
            for (int jj = 0; jj < 8; ++jj) VT[(cc + jj) * 64 + r] = pv[jj];
        }
        __syncthreads();

        // S = Q K^T / 8
        f32x4 s[4];
#pragma unroll
        for (int cb = 0; cb < 4; ++cb) {
            f32x4 z = {};
#pragma unroll
            for (int ds = 0; ds < 2; ++ds) {
                bf16x8 b = *(bf16x8*)(&Kt[(cb * 16 + l16) * 64 + ds * 32 + q * 8]);
                z = __builtin_amdgcn_mfma_f32_16x16x32_bf16(qf[ds], b, z, 0, 0, 0);
            }
            s[cb] = z * 0.125f;
        }

        // online softmax: lane (q, reg r) owns row q*4+r; cols on 16 lanes
        float alpha[4];
#pragma unroll
        for (int r = 0; r < 4; ++r) {
            float mt = fmaxf(fmaxf(s[0][r], s[1][r]), fmaxf(s[2][r], s[3][r]));
#pragma unroll
            for (int off = 1; off < 16; off <<= 1)
                mt = fmaxf(mt, __shfl_xor(mt, off, 64));
            float mn = fmaxf(m_i[r], mt);
            float a = __expf(m_i[r] - mn);
            float rs = 0.f;
#pragma unroll
            for (int cb = 0; cb < 4; ++cb) {
                float p = __expf(s[cb][r] - mn);
                s[cb][r] = p;
                rs += p;
            }
#pragma unroll
            for (int off = 1; off < 16; off <<= 1)
                rs += __shfl_xor(rs, off, 64);
            l_i[r] = l_i[r] * a + rs;
            m_i[r] = mn;
            alpha[r] = a;
        }

        // P -> LDS (C-layout -> A-layout transform), rescale O accumulators
#pragma unroll
        for (int cb = 0; cb < 4; ++cb) {
#pragma unroll
            for (int r = 0; r < 4; ++r) {
                Pt[(wave * 16 + q * 4 + r) * 64 + cb * 16 + l16] = f2b(s[cb][r]);
                oacc[cb][r] *= alpha[r];
            }
        }
        __syncthreads();

        // O += P V
#pragma unroll
        for (int ds = 0; ds < 2; ++ds) {
            bf16x8 ap = *(bf16x8*)(&Pt[(wave * 16 + l16) * 64 + ds * 32 + q * 8]);
#pragma unroll
            for (int db = 0; db < 4; ++db) {
                bf16x8 b = *(bf16x8*)(&VT[(db * 16 + l16) * 64 + ds * 32 + q * 8]);
                oacc[db] = __builtin_amdgcn_mfma_f32_16x16x32_bf16(ap, b, oacc[db], 0, 0, 0);
            }
        }
    }

#pragma unroll
    for (int db = 0; db < 4; ++db)
#pragma unroll
        for (int r = 0; r < 4; ++r) {
            int row = n0 + wave * 16 + q * 4 + r;
            Og[(size_t)row * 64 + db * 16 + l16] = f2b(oacc[db][r] / l_i[r]);
        }
}

// ---------------------------------------------------------------------------
extern "C" void kernel_launch(void* const* d_in, const int* in_sizes, int n_in,
                              void* d_out, int out_size, void* d_ws, size_t ws_size,
                              hipStream_t stream) {
    const float* x   = (const float*)d_in[0];
    const float* w_q = (const float*)d_in[1];
    const float* b_q = (const float*)d_in[2];
    const float* w_k = (const float*)d_in[3];
    const float* b_k = (const float*)d_in[4];
    const float* w_v = (const float*)d_in[5];
    const float* b_v = (const float*)d_in[6];
    const float* w_o = (const float*)d_in[7];
    const float* b_o = (const float*)d_in[8];
    float* out = (float*)d_out;   // reference output dtype is float32

    char* ws = (char*)d_ws;
    u16* xp = (u16*)(ws);                       //  4 MB: (4096, 512) bf16
    u16* Qw = (u16*)(ws + (4ull << 20));        // 16 MB: (16384, 512) bf16
    u16* Kw = (u16*)(ws + (20ull << 20));       //  4 MB: (4096, 512) bf16
    u16* Vw = (u16*)(ws + (24ull << 20));       //  4 MB: (4096, 512) bf16
    u16* Ow = (u16*)(ws + (28ull << 20));       // 16 MB: (16384, 512) bf16

    // 1. avg pool (f32 -> bf16)
    pool_kernel<<<8192, 256, 0, stream>>>(x, xp);
    // 2. Q/K/V projections
    gemm512<false, float, u16><<<dim3(8, 256), 256, 0, stream>>>(x,  w_q, b_q, nullptr, Qw);
    gemm512<false, u16,   u16><<<dim3(8, 64),  256, 0, stream>>>(xp, w_k, b_k, nullptr, Kw);
    gemm512<false, u16,   u16><<<dim3(8, 64),  256, 0, stream>>>(xp, w_v, b_v, nullptr, Vw);
    // 3. attention (32 groups x 64 Q-tiles)
    attn_kernel<<<dim3(64, 32), 256, 0, stream>>>(Qw, Kw, Vw, Ow);
    // 4. output projection + f32 residual, f32 output
    gemm512<true, u16, float><<<dim3(8, 256), 256, 0, stream>>>(Ow, w_o, b_o, x, out);
}

// Round 5
// 365.367 us; speedup vs baseline: 1.3665x; 1.3665x over previous
//
#include <hip/hip_runtime.h>
#include <hip/hip_bf16.h>
#include <math.h>

typedef short bf16x8 __attribute__((ext_vector_type(8)));
typedef float f32x4 __attribute__((ext_vector_type(4)));
typedef unsigned short u16;

__device__ inline float b2f(u16 h) {
    unsigned int u = ((unsigned int)h) << 16;
    float f;
    __builtin_memcpy(&f, &u, 4);
    return f;
}

__device__ inline u16 f2b(float f) {
    unsigned int u;
    __builtin_memcpy(&u, &f, 4);
    unsigned int lsb = (u >> 16) & 1u;
    u += 0x7fffu + lsb;
    return (u16)(u >> 16);
}

// LDS row pitch: 72 u16 = 144 B = 36 dwords -> row r starts at bank (36r)%32;
// 16-lane b128 fragment reads hit each bank <=2-way (free, m136).
#define PITCH 72

// ---------------------------------------------------------------------------
// Prep A: x f32 -> bf16 (8,388,608 elements)
// ---------------------------------------------------------------------------
__global__ __launch_bounds__(256) void cvt_kernel(const float* __restrict__ x,
                                                  u16* __restrict__ xb) {
    int idx = blockIdx.x * 256 + threadIdx.x;   // 2,097,152 float4s
    float4 v = ((const float4*)x)[idx];
    ushort4 o;
    o.x = f2b(v.x); o.y = f2b(v.y); o.z = f2b(v.z); o.w = f2b(v.w);
    ((ushort4*)xb)[idx] = o;
}

// ---------------------------------------------------------------------------
// Prep B: transpose+convert the four 512x512 f32 weights into bf16 WT[n][k].
// Block handles one 64(k) x 64(n) tile; grid (8 n, 8 k, 4 weights).
// ---------------------------------------------------------------------------
__global__ __launch_bounds__(256) void wtrans_kernel(const float* __restrict__ w0,
                                                     const float* __restrict__ w1,
                                                     const float* __restrict__ w2,
                                                     const float* __restrict__ w3,
                                                     u16* __restrict__ wt) {
    const float* W = blockIdx.z == 0 ? w0 : blockIdx.z == 1 ? w1
                   : blockIdx.z == 2 ? w2 : w3;
    u16* WT = wt + (size_t)blockIdx.z * 262144;
    __shared__ u16 T[64 * PITCH];
    int tid = threadIdx.x;
    int nB = blockIdx.x * 64, kB = blockIdx.y * 64;
    // read 64x64 f32 = 1024 float4 chunks, 4 per thread; T[k][n] as bf16
#pragma unroll
    for (int t = 0; t < 4; ++t) {
        int e = tid + t * 256;
        int r = e >> 4, c4 = (e & 15) * 4;
        float4 v = *(const float4*)(&W[(size_t)(kB + r) * 512 + nB + c4]);
        u16* dst = &T[r * PITCH + c4];
        dst[0] = f2b(v.x); dst[1] = f2b(v.y); dst[2] = f2b(v.z); dst[3] = f2b(v.w);
    }
    __syncthreads();
    // write WT[n][k]: lane n=tid&63 gathers 8 k's (consecutive-u16 across
    // lanes -> conflict-free), writes int4
    int n = tid & 63, kg = tid >> 6;
#pragma unroll
    for (int p = 0; p < 2; ++p) {
        int k0 = (kg + p * 4) * 8;
        u16 tmp[8];
#pragma unroll
        for (int i = 0; i < 8; ++i) tmp[i] = T[(k0 + i) * PITCH + n];
        *(int4*)(&WT[(size_t)(nB + n) * 512 + kB + k0]) = *(int4*)tmp;
    }
}

// ---------------------------------------------------------------------------
// Kernel 1: TF avg-pool 3x3/s2 SAME (divide by valid count), from bf16 xb.
// ---------------------------------------------------------------------------
__global__ __launch_bounds__(256) void pool_kernel(const u16* __restrict__ xb,
                                                   u16* __restrict__ xp) {
    int idx = blockIdx.x * 256 + threadIdx.x;   // 2,097,152
    int c = idx & 511;
    int j = (idx >> 9) & 31;
    int i = (idx >> 14) & 31;
    int b = idx >> 19;
    int r0 = 2 * i, c0 = 2 * j;
    int rmax = min(r0 + 3, 64), cmax = min(c0 + 3, 64);
    float s = 0.f;
    for (int r = r0; r < rmax; ++r)
        for (int cc = c0; cc < cmax; ++cc)
            s += b2f(xb[(((b << 6) + r) * 64 + cc) * 512 + c]);
    int cnt = (rmax - r0) * (cmax - c0);
    xp[idx] = f2b(s / (float)cnt);
}

// ---------------------------------------------------------------------------
// Kernel 2: C(Mx512) = A(Mx512,bf16) @ W(512x512) + bias, via WT[n][k] bf16.
// OM=0: bf16 row-major out. OM=1: f32 out + f32 residual. OM=2: bf16 out in
// per-group V^T layout VwT[g][d][m] (g=row>>7, m=(row&127)*8+col/64, d=col&63).
// Tile 128(M)x64(N), BK=64, 4 waves; per wave per k-iter: 16 MFMA.
// ---------------------------------------------------------------------------
template <int OM>
__global__ __launch_bounds__(256) void gemm_bf16(const u16* __restrict__ A,
                                                 const u16* __restrict__ WT,
                                                 const float* __restrict__ bias,
                                                 const float* __restrict__ res,
                                                 void* __restrict__ Cv) {
    __shared__ __align__(16) u16 At[128 * PITCH];
    __shared__ __align__(16) u16 Bt[64 * PITCH];
    int tid = threadIdx.x;
    int lane = tid & 63, wave = tid >> 6;
    int q = lane >> 4, l16 = lane & 15;
    int nBase = blockIdx.x * 64;
    int mBase = blockIdx.y * 128;
    f32x4 acc[2][4] = {};

    for (int kk = 0; kk < 512; kk += 64) {
        __syncthreads();
        // stage A: 128x64 = 1024 int4 chunks, 4/thread
#pragma unroll
        for (int t = 0; t < 4; ++t) {
            int e = tid + t * 256;
            int r = e >> 3, cc = (e & 7) * 8;
            *(int4*)(&At[r * PITCH + cc]) =
                *(const int4*)(&A[(size_t)(mBase + r) * 512 + kk + cc]);
        }
        // stage WT rows: 64x64 = 512 chunks, 2/thread
#pragma unroll
        for (int t = 0; t < 2; ++t) {
            int e = tid + t * 256;
            int r = e >> 3, cc = (e & 7) * 8;
            *(int4*)(&Bt[r * PITCH + cc]) =
                *(const int4*)(&WT[(size_t)(nBase + r) * 512 + kk + cc]);
        }
        __syncthreads();
#pragma unroll
        for (int s = 0; s < 2; ++s) {
#pragma unroll
            for (int ds = 0; ds < 2; ++ds) {
                bf16x8 a = *(bf16x8*)(&At[(wave * 32 + s * 16 + l16) * PITCH + ds * 32 + q * 8]);
#pragma unroll
                for (int cb = 0; cb < 4; ++cb) {
                    bf16x8 b = *(bf16x8*)(&Bt[(cb * 16 + l16) * PITCH + ds * 32 + q * 8]);
                    acc[s][cb] = __builtin_amdgcn_mfma_f32_16x16x32_bf16(a, b, acc[s][cb], 0, 0, 0);
                }
            }
        }
    }

#pragma unroll
    for (int s = 0; s < 2; ++s) {
#pragma unroll
        for (int cb = 0; cb < 4; ++cb) {
            int col = nBase + cb * 16 + l16;
            float bv = bias[col];
#pragma unroll
            for (int r = 0; r < 4; ++r) {
                int row = mBase + wave * 32 + s * 16 + q * 4 + r;
                float v = acc[s][cb][r] + bv;
                if constexpr (OM == 1) {
                    v += res[(size_t)row * 512 + col];
                    ((float*)Cv)[(size_t)row * 512 + col] = v;
                } else if constexpr (OM == 0) {
                    ((u16*)Cv)[(size_t)row * 512 + col] = f2b(v);
                } else {
                    int g = row >> 7, m = ((row & 127) << 3) + (col >> 6), d = col & 63;
                    ((u16*)Cv)[(size_t)((g << 6) + d) * 1024 + m] = f2b(v);
                }
            }
        }
    }
}

// ---------------------------------------------------------------------------
// Kernel 3: flash attention per group. Qg=(4096,64) contiguous, Kg=(1024,64)
// row-major, V pre-transposed per group: VwT[g][d][m] (d<64, m<1024).
// Q-tile 128 rows (wave w owns rows {w*16..+16} of both 64-row halves),
// 16 KV tiles of 64. All LDS rows padded to PITCH=72 (conflict-free).
// ---------------------------------------------------------------------------
__global__ __launch_bounds__(256) void attn_kernel(const u16* __restrict__ Q,
                                                   const u16* __restrict__ K,
                                                   const u16* __restrict__ VT_g,
                                                   u16* __restrict__ O) {
    int g = blockIdx.y;
    int qtile = blockIdx.x;   // 0..31 (128 rows each)
    const u16* Qg = Q + (size_t)g * 262144;
    const u16* Kg = K + (size_t)g * 65536;
    const u16* Vt = VT_g + (size_t)g * 65536;   // [d][m] pitch 1024
    u16* Og = O + (size_t)g * 262144;

    __shared__ __align__(16) u16 Kt[64 * PITCH];    // K[m][d]
    __shared__ __align__(16) u16 VTs[64 * PITCH];   // V^T[d][m-tile]
    __shared__ __align__(16) u16 Pt[128 * PITCH];   // P[n][m]

    int tid = threadIdx.x, lane = tid & 63, wave = tid >> 6;
    int q = lane >> 4, l16 = lane & 15;
    int n0 = qtile * 128;

    bf16x8 qf[2][2];
#pragma unroll
    for (int s = 0; s < 2; ++s)
#pragma unroll
        for (int ds = 0; ds < 2; ++ds)
            qf[s][ds] = *(const bf16x8*)(
                &Qg[(size_t)(n0 + s * 64 + wave * 16 + l16) * 64 + ds * 32 + q * 8]);

    f32x4 oacc[2][4] = {};
    float m_i[2][4], l_i[2][4];
#pragma unroll
    for (int s = 0; s < 2; ++s)
#pragma unroll
        for (int r = 0; r < 4; ++r) { m_i[s][r] = -INFINITY; l_i[s][r] = 0.f; }

    for (int kb = 0; kb < 16; ++kb) {
        __syncthreads();
        // stage K rows and V^T rows: 512 int4 chunks each, 2/thread each
#pragma unroll
        for (int t = 0; t < 2; ++t) {
            int e = tid + t * 256;
            int r = e >> 3, cc = (e & 7) * 8;
            *(int4*)(&Kt[r * PITCH + cc]) =
                *(const int4*)(&Kg[(size_t)(kb * 64 + r) * 64 + cc]);
            *(int4*)(&VTs[r * PITCH + cc]) =
                *(const int4*)(&Vt[(size_t)r * 1024 + kb * 64 + cc]);
        }
        __syncthreads();

        // S = Q K^T / 8 ; online softmax ; P -> Pt (wave-local rows)
#pragma unroll
        for (int s = 0; s < 2; ++s) {
            f32x4 sc[4];
#pragma unroll
            for (int cb = 0; cb < 4; ++cb) {
                f32x4 z = {};
#pragma unroll
                for (int ds = 0; ds < 2; ++ds) {
                    bf16x8 b = *(bf16x8*)(&Kt[(cb * 16 + l16) * PITCH + ds * 32 + q * 8]);
                    z = __builtin_amdgcn_mfma_f32_16x16x32_bf16(qf[s][ds], b, z, 0, 0, 0);
                }
                sc[cb] = z * 0.125f;
            }
            float alpha[4];
#pragma unroll
            for (int r = 0; r < 4; ++r) {
                float mt = fmaxf(fmaxf(sc[0][r], sc[1][r]), fmaxf(sc[2][r], sc[3][r]));
#pragma unroll
                for (int off = 1; off < 16; off <<= 1)
                    mt = fmaxf(mt, __shfl_xor(mt, off, 64));
                float mn = fmaxf(m_i[s][r], mt);
                float a = __expf(m_i[s][r] - mn);
                float rs = 0.f;
#pragma unroll
                for (int cb = 0; cb < 4; ++cb) {
                    float p = __expf(sc[cb][r] - mn);
                    sc[cb][r] = p;
                    rs += p;
                }
#pragma unroll
                for (int off = 1; off < 16; off <<= 1)
                    rs += __shfl_xor(rs, off, 64);
                l_i[s][r] = l_i[s][r] * a + rs;
                m_i[s][r] = mn;
                alpha[r] = a;
            }
#pragma unroll
            for (int cb = 0; cb < 4; ++cb)
#pragma unroll
                for (int r = 0; r < 4; ++r) {
                    Pt[(s * 64 + wave * 16 + q * 4 + r) * PITCH + cb * 16 + l16] = f2b(sc[cb][r]);
                    oacc[s][cb][r] *= alpha[r];
                }
        }
        __syncthreads();

        // O += P V
#pragma unroll
        for (int s = 0; s < 2; ++s)
#pragma unroll
            for (int ds = 0; ds < 2; ++ds) {
                bf16x8 ap = *(bf16x8*)(&Pt[(s * 64 + wave * 16 + l16) * PITCH + ds * 32 + q * 8]);
#pragma unroll
                for (int db = 0; db < 4; ++db) {
                    bf16x8 b = *(bf16x8*)(&VTs[(db * 16 + l16) * PITCH + ds * 32 + q * 8]);
                    oacc[s][db] = __builtin_amdgcn_mfma_f32_16x16x32_bf16(ap, b, oacc[s][db], 0, 0, 0);
                }
            }
    }

#pragma unroll
    for (int s = 0; s < 2; ++s)
#pragma unroll
        for (int db = 0; db < 4; ++db)
#pragma unroll
            for (int r = 0; r < 4; ++r) {
                int row = n0 + s * 64 + wave * 16 + q * 4 + r;
                Og[(size_t)row * 64 + db * 16 + l16] = f2b(oacc[s][db][r] / l_i[s][r]);
            }
}

// ---------------------------------------------------------------------------
extern "C" void kernel_launch(void* const* d_in, const int* in_sizes, int n_in,
                              void* d_out, int out_size, void* d_ws, size_t ws_size,
                              hipStream_t stream) {
    const float* x   = (const float*)d_in[0];
    const float* w_q = (const float*)d_in[1];
    const float* b_q = (const float*)d_in[2];
    const float* w_k = (const float*)d_in[3];
    const float* b_k = (const float*)d_in[4];
    const float* w_v = (const float*)d_in[5];
    const float* b_v = (const float*)d_in[6];
    const float* w_o = (const float*)d_in[7];
    const float* b_o = (const float*)d_in[8];
    float* out = (float*)d_out;

    char* ws = (char*)d_ws;
    u16* xb  = (u16*)(ws);                        // 16 MB (16384,512) bf16
    u16* xp  = (u16*)(ws + (16ull << 20));        //  4 MB (4096,512)
    u16* Qw  = (u16*)(ws + (20ull << 20));        // 16 MB (16384,512)
    u16* Kw  = (u16*)(ws + (36ull << 20));        //  4 MB (4096,512)
    u16* VwT = (u16*)(ws + (40ull << 20));        //  4 MB 32x(64,1024)
    u16* wT  = (u16*)(ws + (44ull << 20));        //  2 MB: 4 x 512x512 bf16
    u16* Ow  = xb;  // alias: xb's last reader (Q-GEMM) precedes attn's write

    // prep
    cvt_kernel<<<8192, 256, 0, stream>>>(x, xb);
    wtrans_kernel<<<dim3(8, 8, 4), 256, 0, stream>>>(w_q, w_k, w_v, w_o, wT);
    // pool
    pool_kernel<<<8192, 256, 0, stream>>>(xb, xp);
    // projections
    gemm_bf16<0><<<dim3(8, 128), 256, 0, stream>>>(xb, wT,            b_q, nullptr, Qw);
    gemm_bf16<0><<<dim3(8, 32),  256, 0, stream>>>(xp, wT + 262144,   b_k, nullptr, Kw);
    gemm_bf16<2><<<dim3(8, 32),  256, 0, stream>>>(xp, wT + 524288,   b_v, nullptr, VwT);
    // attention: 32 q-tiles x 32 groups
    attn_kernel<<<dim3(32, 32), 256, 0, stream>>>(Qw, Kw, VwT, Ow);
    // output projection + residual (f32)
    gemm_bf16<1><<<dim3(8, 128), 256, 0, stream>>>(Ow, wT + 786432, b_o, x, out);
}

// Round 6
// 267.352 us; speedup vs baseline: 1.8675x; 1.3666x over previous
//
#include <hip/hip_runtime.h>
#include <hip/hip_bf16.h>
#include <math.h>

typedef short bf16x8 __attribute__((ext_vector_type(8)));
typedef float f32x4 __attribute__((ext_vector_type(4)));
typedef unsigned short u16;

__device__ inline float b2f(u16 h) {
    unsigned int u = ((unsigned int)h) << 16;
    float f;
    __builtin_memcpy(&f, &u, 4);
    return f;
}

__device__ inline u16 f2b(float f) {
    unsigned int u;
    __builtin_memcpy(&u, &f, 4);
    unsigned int lsb = (u >> 16) & 1u;
    u += 0x7fffu + lsb;
    return (u16)(u >> 16);
}

// async 16B global -> LDS. LDS dest must be wave-uniform base + lane*16;
// all call sites satisfy this (chunk = wave*64 + lane + t*256).
__device__ __forceinline__ void gl2lds16(const u16* g, u16* l) {
    __builtin_amdgcn_global_load_lds(
        (const __attribute__((address_space(1))) unsigned int*)g,
        (__attribute__((address_space(3))) unsigned int*)l,
        16, 0, 0);
}

#define PITCH 72   // wtrans scratch pitch

// ---------------------------------------------------------------------------
// Prep A: x f32 -> bf16
// ---------------------------------------------------------------------------
__global__ __launch_bounds__(256) void cvt_kernel(const float* __restrict__ x,
                                                  u16* __restrict__ xb) {
    int idx = blockIdx.x * 256 + threadIdx.x;   // 2,097,152 float4s
    float4 v = ((const float4*)x)[idx];
    ushort4 o;
    o.x = f2b(v.x); o.y = f2b(v.y); o.z = f2b(v.z); o.w = f2b(v.w);
    ((ushort4*)xb)[idx] = o;
}

// ---------------------------------------------------------------------------
// Prep B: transpose+convert four 512x512 f32 weights into bf16 WT[n][k].
// ---------------------------------------------------------------------------
__global__ __launch_bounds__(256) void wtrans_kernel(const float* __restrict__ w0,
                                                     const float* __restrict__ w1,
                                                     const float* __restrict__ w2,
                                                     const float* __restrict__ w3,
                                                     u16* __restrict__ wt) {
    const float* W = blockIdx.z == 0 ? w0 : blockIdx.z == 1 ? w1
                   : blockIdx.z == 2 ? w2 : w3;
    u16* WT = wt + (size_t)blockIdx.z * 262144;
    __shared__ u16 T[64 * PITCH];
    int tid = threadIdx.x;
    int nB = blockIdx.x * 64, kB = blockIdx.y * 64;
#pragma unroll
    for (int t = 0; t < 4; ++t) {
        int e = tid + t * 256;
        int r = e >> 4, c4 = (e & 15) * 4;
        float4 v = *(const float4*)(&W[(size_t)(kB + r) * 512 + nB + c4]);
        u16* dst = &T[r * PITCH + c4];
        dst[0] = f2b(v.x); dst[1] = f2b(v.y); dst[2] = f2b(v.z); dst[3] = f2b(v.w);
    }
    __syncthreads();
    int n = tid & 63, kg = tid >> 6;
#pragma unroll
    for (int p = 0; p < 2; ++p) {
        int k0 = (kg + p * 4) * 8;
        u16 tmp[8];
#pragma unroll
        for (int i = 0; i < 8; ++i) tmp[i] = T[(k0 + i) * PITCH + n];
        *(int4*)(&WT[(size_t)(nB + n) * 512 + kB + k0]) = *(int4*)tmp;
    }
}

// ---------------------------------------------------------------------------
// Kernel 1: TF avg-pool 3x3/s2 SAME (divide by valid count), bf16 in/out.
// ---------------------------------------------------------------------------
__global__ __launch_bounds__(256) void pool_kernel(const u16* __restrict__ xb,
                                                   u16* __restrict__ xp) {
    int idx = blockIdx.x * 256 + threadIdx.x;   // 2,097,152
    int c = idx & 511;
    int j = (idx >> 9) & 31;
    int i = (idx >> 14) & 31;
    int b = idx >> 19;
    int r0 = 2 * i, c0 = 2 * j;
    int rmax = min(r0 + 3, 64), cmax = min(c0 + 3, 64);
    float s = 0.f;
    for (int r = r0; r < rmax; ++r)
        for (int cc = c0; cc < cmax; ++cc)
            s += b2f(xb[(((b << 6) + r) * 64 + cc) * 512 + c]);
    int cnt = (rmax - r0) * (cmax - c0);
    xp[idx] = f2b(s / (float)cnt);
}

// ---------------------------------------------------------------------------
// Kernel 2: m97-class GEMM. C(Mx512) = A(Mx512,bf16) @ WT(512x512,bf16)^T
// + bias. Tile 128x128, BK=64, 4 waves in 2x2; global_load_lds staging into
// XOR-8 chunk-swizzled LDS (slot kc' = kc ^ (row&7)): b128 frag reads are
// 2-way (free), staging is lane-contiguous.
// OM=0: bf16 row-major. OM=1: f32 + f32 residual. OM=2: bf16 V^T-per-group.
// ---------------------------------------------------------------------------
template <int OM>
__global__ __launch_bounds__(256, 2) void gemm_bf16(const u16* __restrict__ A,
                                                    const u16* __restrict__ WT,
                                                    const float* __restrict__ bias,
                                                    const float* __restrict__ res,
                                                    void* __restrict__ Cv) {
    __shared__ __align__(16) u16 At[128 * 64];
    __shared__ __align__(16) u16 Bt[128 * 64];
    int tid = threadIdx.x, lane = tid & 63, wave = tid >> 6;
    int q = lane >> 4, l16 = lane & 15;
    int wm = wave & 1, wn = wave >> 1;
    int nBase = blockIdx.x * 128, mBase = blockIdx.y * 128;
    f32x4 acc[4][4] = {};

    for (int kk = 0; kk < 512; kk += 64) {
        __syncthreads();
#pragma unroll
        for (int t = 0; t < 4; ++t) {
            int c = wave * 64 + lane + t * 256;       // chunk slot 0..1023
            int m = c >> 3, kc = (c & 7) ^ (m & 7);   // source chunk for slot
            gl2lds16(&A[(size_t)(mBase + m) * 512 + kk + kc * 8], &At[c * 8]);
            gl2lds16(&WT[(size_t)(nBase + m) * 512 + kk + kc * 8], &Bt[c * 8]);
        }
        __syncthreads();
#pragma unroll
        for (int ds = 0; ds < 2; ++ds) {
            bf16x8 a[4], b[4];
#pragma unroll
            for (int i = 0; i < 4; ++i) {
                int ma = wm * 64 + i * 16 + l16;
                a[i] = *(bf16x8*)(&At[ma * 64 + ((((ds << 2) + q) ^ (ma & 7)) << 3)]);
                int nb = wn * 64 + i * 16 + l16;
                b[i] = *(bf16x8*)(&Bt[nb * 64 + ((((ds << 2) + q) ^ (nb & 7)) << 3)]);
            }
#pragma unroll
            for (int i = 0; i < 4; ++i)
#pragma unroll
                for (int j = 0; j < 4; ++j)
                    acc[i][j] = __builtin_amdgcn_mfma_f32_16x16x32_bf16(a[i], b[j], acc[i][j], 0, 0, 0);
        }
    }

#pragma unroll
    for (int j = 0; j < 4; ++j) {
        int col = nBase + wn * 64 + j * 16 + l16;
        float bv = bias[col];
#pragma unroll
        for (int i = 0; i < 4; ++i) {
#pragma unroll
            for (int r = 0; r < 4; ++r) {
                int row = mBase + wm * 64 + i * 16 + q * 4 + r;
                float v = acc[i][j][r] + bv;
                if constexpr (OM == 1) {
                    v += res[(size_t)row * 512 + col];
                    ((float*)Cv)[(size_t)row * 512 + col] = v;
                } else if constexpr (OM == 0) {
                    ((u16*)Cv)[(size_t)row * 512 + col] = f2b(v);
                } else {
                    int g = row >> 7, m2 = ((row & 127) << 3) + (col >> 6), d = col & 63;
                    ((u16*)Cv)[(size_t)((g << 6) + d) * 1024 + m2] = f2b(v);
                }
            }
        }
    }
}

// ---------------------------------------------------------------------------
// Kernel 3: flash attention per group, no-max softmax (scores bounded:
// |s|/8 <~ 6 -> exp safe in fp32), deferred row-sum (no per-iter shfl).
// Q-tile 128 rows, KV-tile 128, 8 iters, 2 barriers/iter (Pt wave-private).
// K/V staged via global_load_lds into XOR-swizzled LDS; Pt padded pitch 136.
// ---------------------------------------------------------------------------
__global__ __launch_bounds__(256, 2) void attn_kernel(const u16* __restrict__ Q,
                                                      const u16* __restrict__ K,
                                                      const u16* __restrict__ VT_g,
                                                      u16* __restrict__ O) {
    int g = blockIdx.y;
    int qtile = blockIdx.x;   // 0..31
    const u16* Qg = Q + (size_t)g * 262144;
    const u16* Kg = K + (size_t)g * 65536;
    const u16* Vt = VT_g + (size_t)g * 65536;   // [d][m], pitch 1024
    u16* Og = O + (size_t)g * 262144;

    __shared__ __align__(16) u16 Kt[128 * 64];    // swizzled [m][d]
    __shared__ __align__(16) u16 VTs[64 * 128];   // swizzled [d][m-tile]
    __shared__ __align__(16) u16 Pt[128 * 136];   // padded   [n][m]

    int tid = threadIdx.x, lane = tid & 63, wave = tid >> 6;
    int q = lane >> 4, l16 = lane & 15;
    int n0 = qtile * 128;

    bf16x8 qf[2][2];
#pragma unroll
    for (int s = 0; s < 2; ++s)
#pragma unroll
        for (int ds = 0; ds < 2; ++ds)
            qf[s][ds] = *(const bf16x8*)(
                &Qg[(size_t)(n0 + s * 64 + wave * 16 + l16) * 64 + ds * 32 + q * 8]);

    f32x4 oacc[2][4] = {};
    float rsum[2][4] = {};

    for (int kb = 0; kb < 8; ++kb) {
        __syncthreads();
#pragma unroll
        for (int t = 0; t < 4; ++t) {
            int c = wave * 64 + lane + t * 256;       // slot 0..1023
            {   // K tile: 128 m-rows x 64 d, XOR-8
                int m = c >> 3, kc = (c & 7) ^ (m & 7);
                gl2lds16(&Kg[(size_t)(kb * 128 + m) * 64 + kc * 8], &Kt[c * 8]);
            }
            {   // V^T tile: 64 d-rows x 128 m, XOR-16
                int d = c >> 4, mc = (c & 15) ^ (d & 15);
                gl2lds16(&Vt[(size_t)d * 1024 + kb * 128 + mc * 8], &VTs[c * 8]);
            }
        }
        __syncthreads();

        // S = Q K^T; p = exp(S/8); accumulate row sums; P -> Pt (wave rows)
#pragma unroll
        for (int s = 0; s < 2; ++s) {
#pragma unroll
            for (int cb = 0; cb < 8; ++cb) {
                f32x4 z = {};
#pragma unroll
                for (int ds = 0; ds < 2; ++ds) {
                    int m = cb * 16 + l16;
                    bf16x8 b = *(bf16x8*)(&Kt[m * 64 + ((((ds << 2) + q) ^ (m & 7)) << 3)]);
                    z = __builtin_amdgcn_mfma_f32_16x16x32_bf16(qf[s][ds], b, z, 0, 0, 0);
                }
#pragma unroll
                for (int r = 0; r < 4; ++r) {
                    // exp(z/8) = 2^(z * log2(e)/8)
                    float p = exp2f(z[r] * 0.18033688011112042f);
                    u16 pb = f2b(p);
                    Pt[(s * 64 + wave * 16 + q * 4 + r) * 136 + cb * 16 + l16] = pb;
                    rsum[s][r] += b2f(pb);
                }
            }
        }
        // Pt rows are wave-private (writer == reader): no barrier needed.
#pragma unroll
        for (int s = 0; s < 2; ++s)
#pragma unroll
            for (int ds = 0; ds < 4; ++ds) {
                bf16x8 ap = *(bf16x8*)(&Pt[(s * 64 + wave * 16 + l16) * 136 + ds * 32 + q * 8]);
#pragma unroll
                for (int db = 0; db < 4; ++db) {
                    int dd = db * 16 + l16;
                    bf16x8 b = *(bf16x8*)(&VTs[dd * 128 + ((((ds << 2) + q) ^ (dd & 15)) << 3)]);
                    oacc[s][db] = __builtin_amdgcn_mfma_f32_16x16x32_bf16(ap, b, oacc[s][db], 0, 0, 0);
                }
            }
    }

    // epilogue: reduce rsum across the 16 col-lanes, then O *= 1/l
#pragma unroll
    for (int s = 0; s < 2; ++s)
#pragma unroll
        for (int r = 0; r < 4; ++r) {
            float v = rsum[s][r];
#pragma unroll
            for (int off = 1; off < 16; off <<= 1)
                v += __shfl_xor(v, off, 64);
            rsum[s][r] = 1.f / v;
        }
#pragma unroll
    for (int s = 0; s < 2; ++s)
#pragma unroll
        for (int db = 0; db < 4; ++db)
#pragma unroll
            for (int r = 0; r < 4; ++r) {
                int row = n0 + s * 64 + wave * 16 + q * 4 + r;
                Og[(size_t)row * 64 + db * 16 + l16] = f2b(oacc[s][db][r] * rsum[s][r]);
            }
}

// ---------------------------------------------------------------------------
extern "C" void kernel_launch(void* const* d_in, const int* in_sizes, int n_in,
                              void* d_out, int out_size, void* d_ws, size_t ws_size,
                              hipStream_t stream) {
    const float* x   = (const float*)d_in[0];
    const float* w_q = (const float*)d_in[1];
    const float* b_q = (const float*)d_in[2];
    const float* w_k = (const float*)d_in[3];
    const float* b_k = (const float*)d_in[4];
    const float* w_v = (const float*)d_in[5];
    const float* b_v = (const float*)d_in[6];
    const float* w_o = (const float*)d_in[7];
    const float* b_o = (const float*)d_in[8];
    float* out = (float*)d_out;

    char* ws = (char*)d_ws;
    u16* xb  = (u16*)(ws);                        // 16 MB (16384,512) bf16
    u16* xp  = (u16*)(ws + (16ull << 20));        //  4 MB (4096,512)
    u16* Qw  = (u16*)(ws + (20ull << 20));        // 16 MB (16384,512)
    u16* Kw  = (u16*)(ws + (36ull << 20));        //  4 MB (4096,512)
    u16* VwT = (u16*)(ws + (40ull << 20));        //  4 MB 32x(64,1024)
    u16* wT  = (u16*)(ws + (44ull << 20));        //  2 MB: 4 x 512x512 bf16
    u16* Ow  = xb;  // alias: xb's last reader (Q-GEMM) precedes attn's write

    cvt_kernel<<<8192, 256, 0, stream>>>(x, xb);
    wtrans_kernel<<<dim3(8, 8, 4), 256, 0, stream>>>(w_q, w_k, w_v, w_o, wT);
    pool_kernel<<<8192, 256, 0, stream>>>(xb, xp);
    gemm_bf16<0><<<dim3(4, 128), 256, 0, stream>>>(xb, wT,          b_q, nullptr, Qw);
    gemm_bf16<0><<<dim3(4, 32),  256, 0, stream>>>(xp, wT + 262144, b_k, nullptr, Kw);
    gemm_bf16<2><<<dim3(4, 32),  256, 0, stream>>>(xp, wT + 524288, b_v, nullptr, VwT);
    attn_kernel<<<dim3(32, 32), 256, 0, stream>>>(Qw, Kw, VwT, Ow);
    gemm_bf16<1><<<dim3(4, 128), 256, 0, stream>>>(Ow, wT + 786432, b_o, x, out);
}

// Round 7
// 251.463 us; speedup vs baseline: 1.9855x; 1.0632x over previous
//
#include <hip/hip_runtime.h>
#include <hip/hip_bf16.h>
#include <math.h>

typedef short bf16x8 __attribute__((ext_vector_type(8)));
typedef float f32x4 __attribute__((ext_vector_type(4)));
typedef unsigned short u16;

__device__ inline float b2f(u16 h) {
    unsigned int u = ((unsigned int)h) << 16;
    float f;
    __builtin_memcpy(&f, &u, 4);
    return f;
}

__device__ inline u16 f2b(float f) {
    unsigned int u;
    __builtin_memcpy(&u, &f, 4);
    unsigned int lsb = (u >> 16) & 1u;
    u += 0x7fffu + lsb;
    return (u16)(u >> 16);
}

// truncating f32->bf16 (round-toward-zero): 1 VALU op
__device__ __forceinline__ u16 f2b_tr(float f) {
    unsigned int u;
    __builtin_memcpy(&u, &f, 4);
    return (u16)(u >> 16);
}

// async 16B global -> LDS. LDS dest must be wave-uniform base + lane*16;
// all call sites satisfy this (chunk = wave*64 + lane + t*256).
__device__ __forceinline__ void gl2lds16(const u16* g, u16* l) {
    __builtin_amdgcn_global_load_lds(
        (const __attribute__((address_space(1))) unsigned int*)g,
        (__attribute__((address_space(3))) unsigned int*)l,
        16, 0, 0);
}

#define PITCH 72   // wtrans scratch / Pt pitch

// log2(e) / 8  (softmax temperature sqrt(64)=8 folded into Q projection)
#define QSCALE 0.18033688011112042f

// ---------------------------------------------------------------------------
// Prep A: x f32 -> bf16
// ---------------------------------------------------------------------------
__global__ __launch_bounds__(256) void cvt_kernel(const float* __restrict__ x,
                                                  u16* __restrict__ xb) {
    int idx = blockIdx.x * 256 + threadIdx.x;   // 2,097,152 float4s
    float4 v = ((const float4*)x)[idx];
    ushort4 o;
    o.x = f2b(v.x); o.y = f2b(v.y); o.z = f2b(v.z); o.w = f2b(v.w);
    ((ushort4*)xb)[idx] = o;
}

// ---------------------------------------------------------------------------
// Prep B: transpose+convert four 512x512 f32 weights into bf16 WT[n][k].
// ---------------------------------------------------------------------------
__global__ __launch_bounds__(256) void wtrans_kernel(const float* __restrict__ w0,
                                                     const float* __restrict__ w1,
                                                     const float* __restrict__ w2,
                                                     const float* __restrict__ w3,
                                                     u16* __restrict__ wt) {
    const float* W = blockIdx.z == 0 ? w0 : blockIdx.z == 1 ? w1
                   : blockIdx.z == 2 ? w2 : w3;
    u16* WT = wt + (size_t)blockIdx.z * 262144;
    __shared__ u16 T[64 * PITCH];
    int tid = threadIdx.x;
    int nB = blockIdx.x * 64, kB = blockIdx.y * 64;
#pragma unroll
    for (int t = 0; t < 4; ++t) {
        int e = tid + t * 256;
        int r = e >> 4, c4 = (e & 15) * 4;
        float4 v = *(const float4*)(&W[(size_t)(kB + r) * 512 + nB + c4]);
        u16* dst = &T[r * PITCH + c4];
        dst[0] = f2b(v.x); dst[1] = f2b(v.y); dst[2] = f2b(v.z); dst[3] = f2b(v.w);
    }
    __syncthreads();
    int n = tid & 63, kg = tid >> 6;
#pragma unroll
    for (int p = 0; p < 2; ++p) {
        int k0 = (kg + p * 4) * 8;
        u16 tmp[8];
#pragma unroll
        for (int i = 0; i < 8; ++i) tmp[i] = T[(k0 + i) * PITCH + n];
        *(int4*)(&WT[(size_t)(nB + n) * 512 + kB + k0]) = *(int4*)tmp;
    }
}

// ---------------------------------------------------------------------------
// Kernel 1: TF avg-pool 3x3/s2 SAME (divide by valid count), bf16 in/out.
// ---------------------------------------------------------------------------
__global__ __launch_bounds__(256) void pool_kernel(const u16* __restrict__ xb,
                                                   u16* __restrict__ xp) {
    int idx = blockIdx.x * 256 + threadIdx.x;   // 2,097,152
    int c = idx & 511;
    int j = (idx >> 9) & 31;
    int i = (idx >> 14) & 31;
    int b = idx >> 19;
    int r0 = 2 * i, c0 = 2 * j;
    int rmax = min(r0 + 3, 64), cmax = min(c0 + 3, 64);
    float s = 0.f;
    for (int r = r0; r < rmax; ++r)
        for (int cc = c0; cc < cmax; ++cc)
            s += b2f(xb[(((b << 6) + r) * 64 + cc) * 512 + c]);
    int cnt = (rmax - r0) * (cmax - c0);
    xp[idx] = f2b(s / (float)cnt);
}

// ---------------------------------------------------------------------------
// Kernel 2: m97-class GEMM. C(Mx512) = (A(Mx512,bf16) @ WT^T + bias) * oscale
// Tile 128x128, BK=64, 4 waves 2x2; global_load_lds into XOR-8 swizzled LDS.
// OM=0: bf16 row-major (scaled). OM=1: f32 + f32 residual. OM=2: V^T-group.
// ---------------------------------------------------------------------------
template <int OM>
__global__ __launch_bounds__(256, 2) void gemm_bf16(const u16* __restrict__ A,
                                                    const u16* __restrict__ WT,
                                                    const float* __restrict__ bias,
                                                    const float* __restrict__ res,
                                                    void* __restrict__ Cv,
                                                    float oscale) {
    __shared__ __align__(16) u16 At[128 * 64];
    __shared__ __align__(16) u16 Bt[128 * 64];
    int tid = threadIdx.x, lane = tid & 63, wave = tid >> 6;
    int q = lane >> 4, l16 = lane & 15;
    int wm = wave & 1, wn = wave >> 1;
    int nBase = blockIdx.x * 128, mBase = blockIdx.y * 128;
    f32x4 acc[4][4] = {};

    for (int kk = 0; kk < 512; kk += 64) {
        __syncthreads();
#pragma unroll
        for (int t = 0; t < 4; ++t) {
            int c = wave * 64 + lane + t * 256;       // chunk slot 0..1023
            int m = c >> 3, kc = (c & 7) ^ (m & 7);   // source chunk for slot
            gl2lds16(&A[(size_t)(mBase + m) * 512 + kk + kc * 8], &At[c * 8]);
            gl2lds16(&WT[(size_t)(nBase + m) * 512 + kk + kc * 8], &Bt[c * 8]);
        }
        __syncthreads();
#pragma unroll
        for (int ds = 0; ds < 2; ++ds) {
            bf16x8 a[4], b[4];
#pragma unroll
            for (int i = 0; i < 4; ++i) {
                int ma = wm * 64 + i * 16 + l16;
                a[i] = *(bf16x8*)(&At[ma * 64 + ((((ds << 2) + q) ^ (ma & 7)) << 3)]);
                int nb = wn * 64 + i * 16 + l16;
                b[i] = *(bf16x8*)(&Bt[nb * 64 + ((((ds << 2) + q) ^ (nb & 7)) << 3)]);
            }
#pragma unroll
            for (int i = 0; i < 4; ++i)
#pragma unroll
                for (int j = 0; j < 4; ++j)
                    acc[i][j] = __builtin_amdgcn_mfma_f32_16x16x32_bf16(a[i], b[j], acc[i][j], 0, 0, 0);
        }
    }

#pragma unroll
    for (int j = 0; j < 4; ++j) {
        int col = nBase + wn * 64 + j * 16 + l16;
        float bv = bias[col];
#pragma unroll
        for (int i = 0; i < 4; ++i) {
#pragma unroll
            for (int r = 0; r < 4; ++r) {
                int row = mBase + wm * 64 + i * 16 + q * 4 + r;
                float v = acc[i][j][r] + bv;
                if constexpr (OM == 1) {
                    v += res[(size_t)row * 512 + col];
                    ((float*)Cv)[(size_t)row * 512 + col] = v;
                } else if constexpr (OM == 0) {
                    ((u16*)Cv)[(size_t)row * 512 + col] = f2b(v * oscale);
                } else {
                    int g = row >> 7, m2 = ((row & 127) << 3) + (col >> 6), d = col & 63;
                    ((u16*)Cv)[(size_t)((g << 6) + d) * 1024 + m2] = f2b(v);
                }
            }
        }
    }
}

// ---------------------------------------------------------------------------
// Kernel 3: flash attention per group. Q pre-scaled by log2(e)/8 so
// p = exp2(z) directly (no-max softmax: |s/8| <~ 6, fp32-safe), deferred
// row-sum, truncating P store. Q-tile 128, KV-tile 128 staged once, then
// processed in two 64-halves against a 64-col Pt (wave-private rows -> no
// inner barriers). 2 barriers/iter, 8 iters. LDS 50 KB -> 3 blocks/CU.
// ---------------------------------------------------------------------------
__global__ __launch_bounds__(256, 3) void attn_kernel(const u16* __restrict__ Q,
                                                      const u16* __restrict__ K,
                                                      const u16* __restrict__ VT_g,
                                                      u16* __restrict__ O) {
    int g = blockIdx.y;
    int qtile = blockIdx.x;   // 0..31
    const u16* Qg = Q + (size_t)g * 262144;
    const u16* Kg = K + (size_t)g * 65536;
    const u16* Vt = VT_g + (size_t)g * 65536;   // [d][m], pitch 1024
    u16* Og = O + (size_t)g * 262144;

    __shared__ __align__(16) u16 Kt[128 * 64];     // swizzled [m][d]
    __shared__ __align__(16) u16 VTs[64 * 128];    // swizzled [d][m-tile]
    __shared__ __align__(16) u16 Pt[128 * PITCH];  // padded   [n][m-half]

    int tid = threadIdx.x, lane = tid & 63, wave = tid >> 6;
    int q = lane >> 4, l16 = lane & 15;
    int n0 = qtile * 128;

    bf16x8 qf[2][2];
#pragma unroll
    for (int s = 0; s < 2; ++s)
#pragma unroll
        for (int ds = 0; ds < 2; ++ds)
            qf[s][ds] = *(const bf16x8*)(
                &Qg[(size_t)(n0 + s * 64 + wave * 16 + l16) * 64 + ds * 32 + q * 8]);

    f32x4 oacc[2][4] = {};
    float rsum[2][4] = {};

    for (int kb = 0; kb < 8; ++kb) {
        __syncthreads();
#pragma unroll
        for (int t = 0; t < 4; ++t) {
            int c = wave * 64 + lane + t * 256;       // slot 0..1023
            {   // K tile: 128 m-rows x 64 d, XOR-8
                int m = c >> 3, kc = (c & 7) ^ (m & 7);
                gl2lds16(&Kg[(size_t)(kb * 128 + m) * 64 + kc * 8], &Kt[c * 8]);
            }
            {   // V^T tile: 64 d-rows x 128 m, XOR-16
                int d = c >> 4, mc = (c & 15) ^ (d & 15);
                gl2lds16(&Vt[(size_t)d * 1024 + kb * 128 + mc * 8], &VTs[c * 8]);
            }
        }
        __syncthreads();

#pragma unroll
        for (int h = 0; h < 2; ++h) {
            // S = Q K^T (h-half); p = exp2(z); P -> Pt (wave-private rows)
#pragma unroll
            for (int s = 0; s < 2; ++s) {
#pragma unroll
                for (int cb = 0; cb < 4; ++cb) {
                    int m = h * 64 + cb * 16 + l16;
                    f32x4 z = {};
#pragma unroll
                    for (int ds = 0; ds < 2; ++ds) {
                        bf16x8 b = *(bf16x8*)(&Kt[m * 64 + ((((ds << 2) + q) ^ (m & 7)) << 3)]);
                        z = __builtin_amdgcn_mfma_f32_16x16x32_bf16(qf[s][ds], b, z, 0, 0, 0);
                    }
#pragma unroll
                    for (int r = 0; r < 4; ++r) {
                        float p = exp2f(z[r]);
                        Pt[(s * 64 + wave * 16 + q * 4 + r) * PITCH + cb * 16 + l16] = f2b_tr(p);
                        rsum[s][r] += p;
                    }
                }
            }
            // O += P V (same wave wrote Pt rows; DS in-order -> no barrier)
#pragma unroll
            for (int s = 0; s < 2; ++s)
#pragma unroll
                for (int ds = 0; ds < 2; ++ds) {
                    bf16x8 ap = *(bf16x8*)(&Pt[(s * 64 + wave * 16 + l16) * PITCH + ds * 32 + q * 8]);
#pragma unroll
                    for (int db = 0; db < 4; ++db) {
                        int dd = db * 16 + l16;
                        int j = h * 8 + ds * 4 + q;
                        bf16x8 b = *(bf16x8*)(&VTs[dd * 128 + ((j ^ (dd & 15)) << 3)]);
                        oacc[s][db] = __builtin_amdgcn_mfma_f32_16x16x32_bf16(ap, b, oacc[s][db], 0, 0, 0);
                    }
                }
        }
    }

    // epilogue: reduce rsum across the 16 col-lanes, then O *= 1/l
#pragma unroll
    for (int s = 0; s < 2; ++s)
#pragma unroll
        for (int r = 0; r < 4; ++r) {
            float v = rsum[s][r];
#pragma unroll
            for (int off = 1; off < 16; off <<= 1)
                v += __shfl_xor(v, off, 64);
            rsum[s][r] = 1.f / v;
        }
#pragma unroll
    for (int s = 0; s < 2; ++s)
#pragma unroll
        for (int db = 0; db < 4; ++db)
#pragma unroll
            for (int r = 0; r < 4; ++r) {
                int row = n0 + s * 64 + wave * 16 + q * 4 + r;
                Og[(size_t)row * 64 + db * 16 + l16] = f2b(oacc[s][db][r] * rsum[s][r]);
            }
}

// ---------------------------------------------------------------------------
extern "C" void kernel_launch(void* const* d_in, const int* in_sizes, int n_in,
                              void* d_out, int out_size, void* d_ws, size_t ws_size,
                              hipStream_t stream) {
    const float* x   = (const float*)d_in[0];
    const float* w_q = (const float*)d_in[1];
    const float* b_q = (const float*)d_in[2];
    const float* w_k = (const float*)d_in[3];
    const float* b_k = (const float*)d_in[4];
    const float* w_v = (const float*)d_in[5];
    const float* b_v = (const float*)d_in[6];
    const float* w_o = (const float*)d_in[7];
    const float* b_o = (const float*)d_in[8];
    float* out = (float*)d_out;

    char* ws = (char*)d_ws;
    u16* xb  = (u16*)(ws);                        // 16 MB (16384,512) bf16
    u16* xp  = (u16*)(ws + (16ull << 20));        //  4 MB (4096,512)
    u16* Qw  = (u16*)(ws + (20ull << 20));        // 16 MB (16384,512)
    u16* Kw  = (u16*)(ws + (36ull << 20));        //  4 MB (4096,512)
    u16* VwT = (u16*)(ws + (40ull << 20));        //  4 MB 32x(64,1024)
    u16* wT  = (u16*)(ws + (44ull << 20));        //  2 MB: 4 x 512x512 bf16
    u16* Ow  = xb;  // alias: xb's last reader (Q-GEMM) precedes attn's write

    cvt_kernel<<<8192, 256, 0, stream>>>(x, xb);
    wtrans_kernel<<<dim3(8, 8, 4), 256, 0, stream>>>(w_q, w_k, w_v, w_o, wT);
    pool_kernel<<<8192, 256, 0, stream>>>(xb, xp);
    gemm_bf16<0><<<dim3(4, 128), 256, 0, stream>>>(xb, wT,          b_q, nullptr, Qw, QSCALE);
    gemm_bf16<0><<<dim3(4, 32),  256, 0, stream>>>(xp, wT + 262144, b_k, nullptr, Kw, 1.0f);
    gemm_bf16<2><<<dim3(4, 32),  256, 0, stream>>>(xp, wT + 524288, b_v, nullptr, VwT, 1.0f);
    attn_kernel<<<dim3(32, 32), 256, 0, stream>>>(Qw, Kw, VwT, Ow);
    gemm_bf16<1><<<dim3(4, 128), 256, 0, stream>>>(Ow, wT + 786432, b_o, x, out, 1.0f);
}

// Round 8
// 243.127 us; speedup vs baseline: 2.0535x; 1.0343x over previous
//
#include <hip/hip_runtime.h>
#include <hip/hip_bf16.h>
#include <math.h>

typedef short bf16x8 __attribute__((ext_vector_type(8)));
typedef float f32x4 __attribute__((ext_vector_type(4)));
typedef unsigned short u16;

__device__ inline float b2f(u16 h) {
    unsigned int u = ((unsigned int)h) << 16;
    float f;
    __builtin_memcpy(&f, &u, 4);
    return f;
}

__device__ inline u16 f2b(float f) {
    unsigned int u;
    __builtin_memcpy(&u, &f, 4);
    unsigned int lsb = (u >> 16) & 1u;
    u += 0x7fffu + lsb;
    return (u16)(u >> 16);
}

// async 16B global -> LDS (wave-uniform base + lane*16 at all call sites)
__device__ __forceinline__ void gl2lds16(const u16* g, u16* l) {
    __builtin_amdgcn_global_load_lds(
        (const __attribute__((address_space(1))) unsigned int*)g,
        (__attribute__((address_space(3))) unsigned int*)l,
        16, 0, 0);
}

#define PITCH 72   // wtrans scratch pitch

// log2(e) / 8  (softmax temperature sqrt(64)=8 folded into Q projection)
#define QSCALE 0.18033688011112042f

// ---------------------------------------------------------------------------
// Prep A: x f32 -> bf16
// ---------------------------------------------------------------------------
__global__ __launch_bounds__(256) void cvt_kernel(const float* __restrict__ x,
                                                  u16* __restrict__ xb) {
    int idx = blockIdx.x * 256 + threadIdx.x;   // 2,097,152 float4s
    float4 v = ((const float4*)x)[idx];
    ushort4 o;
    o.x = f2b(v.x); o.y = f2b(v.y); o.z = f2b(v.z); o.w = f2b(v.w);
    ((ushort4*)xb)[idx] = o;
}

// ---------------------------------------------------------------------------
// Prep B: transpose+convert four 512x512 f32 weights into bf16 WT[n][k].
// Order: q, k, v, o (k and v adjacent -> fused KV GEMM sees 1024 N-rows).
// ---------------------------------------------------------------------------
__global__ __launch_bounds__(256) void wtrans_kernel(const float* __restrict__ w0,
                                                     const float* __restrict__ w1,
                                                     const float* __restrict__ w2,
                                                     const float* __restrict__ w3,
                                                     u16* __restrict__ wt) {
    const float* W = blockIdx.z == 0 ? w0 : blockIdx.z == 1 ? w1
                   : blockIdx.z == 2 ? w2 : w3;
    u16* WT = wt + (size_t)blockIdx.z * 262144;
    __shared__ u16 T[64 * PITCH];
    int tid = threadIdx.x;
    int nB = blockIdx.x * 64, kB = blockIdx.y * 64;
#pragma unroll
    for (int t = 0; t < 4; ++t) {
        int e = tid + t * 256;
        int r = e >> 4, c4 = (e & 15) * 4;
        float4 v = *(const float4*)(&W[(size_t)(kB + r) * 512 + nB + c4]);
        u16* dst = &T[r * PITCH + c4];
        dst[0] = f2b(v.x); dst[1] = f2b(v.y); dst[2] = f2b(v.z); dst[3] = f2b(v.w);
    }
    __syncthreads();
    int n = tid & 63, kg = tid >> 6;
#pragma unroll
    for (int p = 0; p < 2; ++p) {
        int k0 = (kg + p * 4) * 8;
        u16 tmp[8];
#pragma unroll
        for (int i = 0; i < 8; ++i) tmp[i] = T[(k0 + i) * PITCH + n];
        *(int4*)(&WT[(size_t)(nB + n) * 512 + kB + k0]) = *(int4*)tmp;
    }
}

// ---------------------------------------------------------------------------
// Kernel 1: TF avg-pool 3x3/s2 SAME (divide by valid count), bf16 in/out.
// Vectorized: one thread = 8 channels (b128 loads/stores).
// ---------------------------------------------------------------------------
__global__ __launch_bounds__(256) void pool_kernel(const u16* __restrict__ xb,
                                                   u16* __restrict__ xp) {
    int idx = blockIdx.x * 256 + threadIdx.x;   // 262,144 = (4,32,32,64)
    int c8 = idx & 63;
    int j = (idx >> 6) & 31;
    int i = (idx >> 11) & 31;
    int b = idx >> 16;
    int r0 = 2 * i, c0 = 2 * j;
    int rmax = min(r0 + 3, 64), cmax = min(c0 + 3, 64);
    float acc[8] = {};
    for (int r = r0; r < rmax; ++r)
        for (int cc = c0; cc < cmax; ++cc) {
            bf16x8 v = *(const bf16x8*)(
                &xb[(size_t)((((b << 6) + r) << 6) + cc) * 512 + c8 * 8]);
#pragma unroll
            for (int t = 0; t < 8; ++t) acc[t] += b2f(((const u16*)&v)[t]);
        }
    float inv = 1.f / (float)((rmax - r0) * (cmax - c0));
    u16 o[8];
#pragma unroll
    for (int t = 0; t < 8; ++t) o[t] = f2b(acc[t] * inv);
    *(int4*)(&xp[(size_t)idx * 8]) = *(int4*)o;
}

// ---------------------------------------------------------------------------
// Kernel 2: m97-class GEMM. Tile 128x128, BK=64, 4 waves 2x2; global_load_lds
// into XOR-8 swizzled LDS. OM=0: bf16 row-major * oscale. OM=1: f32 + f32
// residual. OM=3: fused K|V (N=1024): cols<512 -> Kw row-major, cols>=512 ->
// V^T per-group layout into Cv2.
// ---------------------------------------------------------------------------
template <int OM>
__global__ __launch_bounds__(256, 2) void gemm_bf16(const u16* __restrict__ A,
                                                    const u16* __restrict__ WT,
                                                    const float* __restrict__ bias,
                                                    const float* __restrict__ bias2res,
                                                    void* __restrict__ Cv,
                                                    void* __restrict__ Cv2,
                                                    float oscale) {
    __shared__ __align__(16) u16 At[128 * 64];
    __shared__ __align__(16) u16 Bt[128 * 64];
    int tid = threadIdx.x, lane = tid & 63, wave = tid >> 6;
    int q = lane >> 4, l16 = lane & 15;
    int wm = wave & 1, wn = wave >> 1;
    int nBase = blockIdx.x * 128, mBase = blockIdx.y * 128;
    f32x4 acc[4][4] = {};

    for (int kk = 0; kk < 512; kk += 64) {
        __syncthreads();
#pragma unroll
        for (int t = 0; t < 4; ++t) {
            int c = wave * 64 + lane + t * 256;       // chunk slot 0..1023
            int m = c >> 3, kc = (c & 7) ^ (m & 7);   // source chunk for slot
            gl2lds16(&A[(size_t)(mBase + m) * 512 + kk + kc * 8], &At[c * 8]);
            gl2lds16(&WT[(size_t)(nBase + m) * 512 + kk + kc * 8], &Bt[c * 8]);
        }
        __syncthreads();
#pragma unroll
        for (int ds = 0; ds < 2; ++ds) {
            bf16x8 a[4], b[4];
#pragma unroll
            for (int i = 0; i < 4; ++i) {
                int ma = wm * 64 + i * 16 + l16;
                a[i] = *(bf16x8*)(&At[ma * 64 + ((((ds << 2) + q) ^ (ma & 7)) << 3)]);
                int nb = wn * 64 + i * 16 + l16;
                b[i] = *(bf16x8*)(&Bt[nb * 64 + ((((ds << 2) + q) ^ (nb & 7)) << 3)]);
            }
#pragma unroll
            for (int i = 0; i < 4; ++i)
#pragma unroll
                for (int j = 0; j < 4; ++j)
                    acc[i][j] = __builtin_amdgcn_mfma_f32_16x16x32_bf16(a[i], b[j], acc[i][j], 0, 0, 0);
        }
    }

    bool isK = (OM != 3) || (nBase < 512);
#pragma unroll
    for (int j = 0; j < 4; ++j) {
        int col = nBase + wn * 64 + j * 16 + l16;
        float bv;
        if constexpr (OM == 3) bv = isK ? bias[col] : bias2res[col - 512];
        else bv = bias[col];
#pragma unroll
        for (int i = 0; i < 4; ++i) {
#pragma unroll
            for (int r = 0; r < 4; ++r) {
                int row = mBase + wm * 64 + i * 16 + q * 4 + r;
                float v = acc[i][j][r] + bv;
                if constexpr (OM == 1) {
                    v += bias2res[(size_t)row * 512 + col];
                    ((float*)Cv)[(size_t)row * 512 + col] = v;
                } else if constexpr (OM == 0) {
                    ((u16*)Cv)[(size_t)row * 512 + col] = f2b(v * oscale);
                } else {
                    if (isK) {
                        ((u16*)Cv)[(size_t)row * 512 + col] = f2b(v);
                    } else {
                        int colv = col - 512;
                        int g = row >> 7, m2 = ((row & 127) << 3) + (colv >> 6), d = colv & 63;
                        ((u16*)Cv2)[(size_t)((g << 6) + d) * 1024 + m2] = f2b(v);
                    }
                }
            }
        }
    }
}

// ---------------------------------------------------------------------------
// Kernel 3: flash attention per group, S^T formulation.
// S^T = mfma(A=K-frag, B=Q-frag): C gives lane (q,l16) 4 values at
// (m = cb*16+q*4+r, n = l16) -> Pt[n][m] write is one packed ds_write_b64.
// rsum indexed by n=l16 only (quad-reduced in epilogue). Pt 64x64 with
// XOR-4-dword swizzle (key 4*(l16&7)): b64 writes & b128 reads bank-uniform.
// LDS = 16K(Kt)+16K(VTs)+8K(Pt) = 40960 B -> exactly 4 blocks/CU; grid 1024
// = one full round. No-max softmax (|s/8| <~ 6, fp32-safe), Q pre-scaled by
// log2(e)/8 so p = exp2(z). 2 barriers/iter; Pt rows wave-private.
// ---------------------------------------------------------------------------
__global__ __launch_bounds__(256, 4) void attn_kernel(const u16* __restrict__ Q,
                                                      const u16* __restrict__ K,
                                                      const u16* __restrict__ VT_g,
                                                      u16* __restrict__ O) {
    int g = blockIdx.y;
    int qtile = blockIdx.x;   // 0..31
    const u16* Qg = Q + (size_t)g * 262144;
    const u16* Kg = K + (size_t)g * 65536;
    const u16* Vt = VT_g + (size_t)g * 65536;   // [d][m], pitch 1024
    u16* Og = O + (size_t)g * 262144;

    __shared__ __align__(16) u16 Kt[128 * 64];    // XOR-8 swizzled [m][d]
    __shared__ __align__(16) u16 VTs[64 * 128];   // XOR-16 swizzled [d][m]
    __shared__ __align__(16) u16 Pt[64 * 64];     // XOR-4dw swizzled [n][m-half]

    int tid = threadIdx.x, lane = tid & 63, wave = tid >> 6;
    int q = lane >> 4, l16 = lane & 15;
    int n0 = qtile * 128;
    int pkey = (l16 & 7) << 2;            // dword-XOR key for Pt
    int prow = (wave * 16 + l16) * 32;    // Pt row base (dwords)
    int* Pt32 = (int*)Pt;

    bf16x8 qf[2][2];
#pragma unroll
    for (int s = 0; s < 2; ++s)
#pragma unroll
        for (int ds = 0; ds < 2; ++ds)
            qf[s][ds] = *(const bf16x8*)(
                &Qg[(size_t)(n0 + s * 64 + wave * 16 + l16) * 64 + ds * 32 + q * 8]);

    f32x4 oacc[2][4] = {};
    float rsum[2] = {0.f, 0.f};

    for (int kb = 0; kb < 8; ++kb) {
        __syncthreads();
#pragma unroll
        for (int t = 0; t < 4; ++t) {
            int c = wave * 64 + lane + t * 256;       // slot 0..1023
            {   // K tile: 128 m-rows x 64 d, XOR-8
                int m = c >> 3, kc = (c & 7) ^ (m & 7);
                gl2lds16(&Kg[(size_t)(kb * 128 + m) * 64 + kc * 8], &Kt[c * 8]);
            }
            {   // V^T tile: 64 d-rows x 128 m, XOR-16
                int d = c >> 4, mc = (c & 15) ^ (d & 15);
                gl2lds16(&Vt[(size_t)d * 1024 + kb * 128 + mc * 8], &VTs[c * 8]);
            }
        }
        __syncthreads();

#pragma unroll
        for (int h = 0; h < 2; ++h) {
            // K fragments for this half (A-operand), reused for both s
            bf16x8 kf[4][2];
#pragma unroll
            for (int cb = 0; cb < 4; ++cb)
#pragma unroll
                for (int ds = 0; ds < 2; ++ds) {
                    int m = h * 64 + cb * 16 + l16;
                    kf[cb][ds] = *(bf16x8*)(&Kt[m * 64 + ((((ds << 2) + q) ^ (m & 7)) << 3)]);
                }
#pragma unroll
            for (int s = 0; s < 2; ++s) {
                // S^T block; p = exp2(z); packed b64 write to Pt[n][m]
#pragma unroll
                for (int cb = 0; cb < 4; ++cb) {
                    f32x4 z = {};
                    z = __builtin_amdgcn_mfma_f32_16x16x32_bf16(kf[cb][0], qf[s][0], z, 0, 0, 0);
                    z = __builtin_amdgcn_mfma_f32_16x16x32_bf16(kf[cb][1], qf[s][1], z, 0, 0, 0);
                    float p0 = exp2f(z[0]), p1 = exp2f(z[1]);
                    float p2 = exp2f(z[2]), p3 = exp2f(z[3]);
                    rsum[s] += (p0 + p1) + (p2 + p3);
                    unsigned a0, a1, a2, a3;
                    __builtin_memcpy(&a0, &p0, 4); __builtin_memcpy(&a1, &p1, 4);
                    __builtin_memcpy(&a2, &p2, 4); __builtin_memcpy(&a3, &p3, 4);
                    int2 w;
                    w.x = (int)((a0 >> 16) | (a1 & 0xffff0000u));
                    w.y = (int)((a2 >> 16) | (a3 & 0xffff0000u));
                    int pd = (cb * 8 + q * 2) ^ pkey;
                    *(int2*)(&Pt32[prow + pd]) = w;
                }
                // O += P V (same wave wrote Pt rows; DS in-order, no barrier)
#pragma unroll
                for (int ds = 0; ds < 2; ++ds) {
                    int pd = (ds * 16 + q * 4) ^ pkey;
                    bf16x8 ap = *(bf16x8*)(&Pt32[prow + pd]);
#pragma unroll
                    for (int db = 0; db < 4; ++db) {
                        int dd = db * 16 + l16;
                        int jj = h * 8 + ds * 4 + q;
                        bf16x8 vb = *(bf16x8*)(&VTs[dd * 128 + ((jj ^ (dd & 15)) << 3)]);
                        oacc[s][db] = __builtin_amdgcn_mfma_f32_16x16x32_bf16(ap, vb, oacc[s][db], 0, 0, 0);
                    }
                }
            }
        }
    }

    // epilogue: rsum lives at row n=l16 (partial over quads) -> reduce over
    // quads, then fetch row (q*4+r)'s total via shfl, normalize, store.
#pragma unroll
    for (int s = 0; s < 2; ++s) {
        float v = rsum[s];
        v += __shfl_xor(v, 16, 64);
        v += __shfl_xor(v, 32, 64);
        rsum[s] = v;
    }
    float inv[2][4];
#pragma unroll
    for (int s = 0; s < 2; ++s)
#pragma unroll
        for (int r = 0; r < 4; ++r)
            inv[s][r] = 1.f / __shfl(rsum[s], q * 4 + r, 64);
#pragma unroll
    for (int s = 0; s < 2; ++s)
#pragma unroll
        for (int db = 0; db < 4; ++db)
#pragma unroll
            for (int r = 0; r < 4; ++r) {
                int row = n0 + s * 64 + wave * 16 + q * 4 + r;
                Og[(size_t)row * 64 + db * 16 + l16] = f2b(oacc[s][db][r] * inv[s][r]);
            }
}

// ---------------------------------------------------------------------------
extern "C" void kernel_launch(void* const* d_in, const int* in_sizes, int n_in,
                              void* d_out, int out_size, void* d_ws, size_t ws_size,
                              hipStream_t stream) {
    const float* x   = (const float*)d_in[0];
    const float* w_q = (const float*)d_in[1];
    const float* b_q = (const float*)d_in[2];
    const float* w_k = (const float*)d_in[3];
    const float* b_k = (const float*)d_in[4];
    const float* w_v = (const float*)d_in[5];
    const float* b_v = (const float*)d_in[6];
    const float* w_o = (const float*)d_in[7];
    const float* b_o = (const float*)d_in[8];
    float* out = (float*)d_out;

    char* ws = (char*)d_ws;
    u16* xb  = (u16*)(ws);                        // 16 MB (16384,512) bf16
    u16* xp  = (u16*)(ws + (16ull << 20));        //  4 MB (4096,512)
    u16* Qw  = (u16*)(ws + (20ull << 20));        // 16 MB (16384,512)
    u16* Kw  = (u16*)(ws + (36ull << 20));        //  4 MB (4096,512)
    u16* VwT = (u16*)(ws + (40ull << 20));        //  4 MB 32x(64,1024)
    u16* wT  = (u16*)(ws + (44ull << 20));        //  2 MB: 4 x 512x512 bf16
    u16* Ow  = xb;  // alias: xb's last reader (Q-GEMM) precedes attn's write

    cvt_kernel<<<8192, 256, 0, stream>>>(x, xb);
    wtrans_kernel<<<dim3(8, 8, 4), 256, 0, stream>>>(w_q, w_k, w_v, w_o, wT);
    pool_kernel<<<1024, 256, 0, stream>>>(xb, xp);
    // Q projection (scaled by log2(e)/8)
    gemm_bf16<0><<<dim3(4, 128), 256, 0, stream>>>(xb, wT, b_q, nullptr, Qw, nullptr, QSCALE);
    // fused K|V projection (N=1024 over adjacent K^T,V^T weights)
    gemm_bf16<3><<<dim3(8, 32), 256, 0, stream>>>(xp, wT + 262144, b_k, b_v, Kw, VwT, 1.0f);
    // attention: 32 q-tiles x 32 groups
    attn_kernel<<<dim3(32, 32), 256, 0, stream>>>(Qw, Kw, VwT, Ow);
    // output projection + f32 residual
    gemm_bf16<1><<<dim3(4, 128), 256, 0, stream>>>(Ow, wT + 786432, b_o, x, out, nullptr, 1.0f);
}

// Round 9
// 237.946 us; speedup vs baseline: 2.0983x; 1.0218x over previous
//
#include <hip/hip_runtime.h>
#include <hip/hip_bf16.h>
#include <math.h>

typedef short bf16x8 __attribute__((ext_vector_type(8)));
typedef float f32x4 __attribute__((ext_vector_type(4)));
typedef unsigned short u16;

__device__ inline float b2f(u16 h) {
    unsigned int u = ((unsigned int)h) << 16;
    float f;
    __builtin_memcpy(&f, &u, 4);
    return f;
}

__device__ inline u16 f2b(float f) {
    unsigned int u;
    __builtin_memcpy(&u, &f, 4);
    unsigned int lsb = (u >> 16) & 1u;
    u += 0x7fffu + lsb;
    return (u16)(u >> 16);
}

// async 16B global -> LDS (wave-uniform base + lane*16 at all call sites)
__device__ __forceinline__ void gl2lds16(const u16* g, u16* l) {
    __builtin_amdgcn_global_load_lds(
        (const __attribute__((address_space(1))) unsigned int*)g,
        (__attribute__((address_space(3))) unsigned int*)l,
        16, 0, 0);
}

#define PITCH 72   // wtrans scratch pitch

// log2(e) / 8  (softmax temperature sqrt(64)=8 folded into Q projection)
#define QSCALE 0.18033688011112042f

// ---------------------------------------------------------------------------
// Prep A: x f32 -> bf16
// ---------------------------------------------------------------------------
__global__ __launch_bounds__(256) void cvt_kernel(const float* __restrict__ x,
                                                  u16* __restrict__ xb) {
    int idx = blockIdx.x * 256 + threadIdx.x;   // 2,097,152 float4s
    float4 v = ((const float4*)x)[idx];
    ushort4 o;
    o.x = f2b(v.x); o.y = f2b(v.y); o.z = f2b(v.z); o.w = f2b(v.w);
    ((ushort4*)xb)[idx] = o;
}

// ---------------------------------------------------------------------------
// Prep B: transpose+convert four 512x512 f32 weights into bf16 WT[n][k].
// Order: q, k, v, o (k and v adjacent -> fused KV GEMM sees 1024 N-rows).
// ---------------------------------------------------------------------------
__global__ __launch_bounds__(256) void wtrans_kernel(const float* __restrict__ w0,
                                                     const float* __restrict__ w1,
                                                     const float* __restrict__ w2,
                                                     const float* __restrict__ w3,
                                                     u16* __restrict__ wt) {
    const float* W = blockIdx.z == 0 ? w0 : blockIdx.z == 1 ? w1
                   : blockIdx.z == 2 ? w2 : w3;
    u16* WT = wt + (size_t)blockIdx.z * 262144;
    __shared__ u16 T[64 * PITCH];
    int tid = threadIdx.x;
    int nB = blockIdx.x * 64, kB = blockIdx.y * 64;
#pragma unroll
    for (int t = 0; t < 4; ++t) {
        int e = tid + t * 256;
        int r = e >> 4, c4 = (e & 15) * 4;
        float4 v = *(const float4*)(&W[(size_t)(kB + r) * 512 + nB + c4]);
        u16* dst = &T[r * PITCH + c4];
        dst[0] = f2b(v.x); dst[1] = f2b(v.y); dst[2] = f2b(v.z); dst[3] = f2b(v.w);
    }
    __syncthreads();
    int n = tid & 63, kg = tid >> 6;
#pragma unroll
    for (int p = 0; p < 2; ++p) {
        int k0 = (kg + p * 4) * 8;
        u16 tmp[8];
#pragma unroll
        for (int i = 0; i < 8; ++i) tmp[i] = T[(k0 + i) * PITCH + n];
        *(int4*)(&WT[(size_t)(nB + n) * 512 + kB + k0]) = *(int4*)tmp;
    }
}

// ---------------------------------------------------------------------------
// Kernel 1: TF avg-pool 3x3/s2 SAME (divide by valid count), bf16 in/out.
// Vectorized: one thread = 8 channels (b128 loads/stores).
// ---------------------------------------------------------------------------
__global__ __launch_bounds__(256) void pool_kernel(const u16* __restrict__ xb,
                                                   u16* __restrict__ xp) {
    int idx = blockIdx.x * 256 + threadIdx.x;   // 262,144 = (4,32,32,64)
    int c8 = idx & 63;
    int j = (idx >> 6) & 31;
    int i = (idx >> 11) & 31;
    int b = idx >> 16;
    int r0 = 2 * i, c0 = 2 * j;
    int rmax = min(r0 + 3, 64), cmax = min(c0 + 3, 64);
    float acc[8] = {};
    for (int r = r0; r < rmax; ++r)
        for (int cc = c0; cc < cmax; ++cc) {
            bf16x8 v = *(const bf16x8*)(
                &xb[(size_t)((((b << 6) + r) << 6) + cc) * 512 + c8 * 8]);
#pragma unroll
            for (int t = 0; t < 8; ++t) acc[t] += b2f(((const u16*)&v)[t]);
        }
    float inv = 1.f / (float)((rmax - r0) * (cmax - c0));
    u16 o[8];
#pragma unroll
    for (int t = 0; t < 8; ++t) o[t] = f2b(acc[t] * inv);
    *(int4*)(&xp[(size_t)idx * 8]) = *(int4*)o;
}

// ---------------------------------------------------------------------------
// Kernel 2: m97-class GEMM. Tile 128x128, BK=64, 4 waves 2x2; global_load_lds
// into XOR-8 swizzled LDS. OM=0: bf16 row-major * oscale. OM=1: f32 + f32
// residual. OM=3: fused K|V (N=1024): cols<512 -> Kw row-major, cols>=512 ->
// V^T per-group layout into Cv2.
// ---------------------------------------------------------------------------
template <int OM>
__global__ __launch_bounds__(256, 2) void gemm_bf16(const u16* __restrict__ A,
                                                    const u16* __restrict__ WT,
                                                    const float* __restrict__ bias,
                                                    const float* __restrict__ bias2res,
                                                    void* __restrict__ Cv,
                                                    void* __restrict__ Cv2,
                                                    float oscale) {
    __shared__ __align__(16) u16 At[128 * 64];
    __shared__ __align__(16) u16 Bt[128 * 64];
    int tid = threadIdx.x, lane = tid & 63, wave = tid >> 6;
    int q = lane >> 4, l16 = lane & 15;
    int wm = wave & 1, wn = wave >> 1;
    int nBase = blockIdx.x * 128, mBase = blockIdx.y * 128;
    f32x4 acc[4][4] = {};

    for (int kk = 0; kk < 512; kk += 64) {
        __syncthreads();
#pragma unroll
        for (int t = 0; t < 4; ++t) {
            int c = wave * 64 + lane + t * 256;       // chunk slot 0..1023
            int m = c >> 3, kc = (c & 7) ^ (m & 7);   // source chunk for slot
            gl2lds16(&A[(size_t)(mBase + m) * 512 + kk + kc * 8], &At[c * 8]);
            gl2lds16(&WT[(size_t)(nBase + m) * 512 + kk + kc * 8], &Bt[c * 8]);
        }
        __syncthreads();
#pragma unroll
        for (int ds = 0; ds < 2; ++ds) {
            bf16x8 a[4], b[4];
#pragma unroll
            for (int i = 0; i < 4; ++i) {
                int ma = wm * 64 + i * 16 + l16;
                a[i] = *(bf16x8*)(&At[ma * 64 + ((((ds << 2) + q) ^ (ma & 7)) << 3)]);
                int nb = wn * 64 + i * 16 + l16;
                b[i] = *(bf16x8*)(&Bt[nb * 64 + ((((ds << 2) + q) ^ (nb & 7)) << 3)]);
            }
#pragma unroll
            for (int i = 0; i < 4; ++i)
#pragma unroll
                for (int j = 0; j < 4; ++j)
                    acc[i][j] = __builtin_amdgcn_mfma_f32_16x16x32_bf16(a[i], b[j], acc[i][j], 0, 0, 0);
        }
    }

    bool isK = (OM != 3) || (nBase < 512);
#pragma unroll
    for (int j = 0; j < 4; ++j) {
        int col = nBase + wn * 64 + j * 16 + l16;
        float bv;
        if constexpr (OM == 3) bv = isK ? bias[col] : bias2res[col - 512];
        else bv = bias[col];
#pragma unroll
        for (int i = 0; i < 4; ++i) {
#pragma unroll
            for (int r = 0; r < 4; ++r) {
                int row = mBase + wm * 64 + i * 16 + q * 4 + r;
                float v = acc[i][j][r] + bv;
                if constexpr (OM == 1) {
                    v += bias2res[(size_t)row * 512 + col];
                    ((float*)Cv)[(size_t)row * 512 + col] = v;
                } else if constexpr (OM == 0) {
                    ((u16*)Cv)[(size_t)row * 512 + col] = f2b(v * oscale);
                } else {
                    if (isK) {
                        ((u16*)Cv)[(size_t)row * 512 + col] = f2b(v);
                    } else {
                        int colv = col - 512;
                        int g = row >> 7, m2 = ((row & 127) << 3) + (colv >> 6), d = colv & 63;
                        ((u16*)Cv2)[(size_t)((g << 6) + d) * 1024 + m2] = f2b(v);
                    }
                }
            }
        }
    }
}

// ---------------------------------------------------------------------------
// Kernel 3: flash attention per group, S^T formulation.
// S^T = mfma(A=K-frag, B=Q-frag): lane (q,l16) gets 4 values at consecutive
// m -> Pt[n][m] write is one packed ds_write_b64; rsum indexed by n=l16.
// kf fragments are loaded per (h,s,cb) as transients (8 VGPRs) -- NOT
// hoisted: at __launch_bounds__(256,4) the unified VGPR/AGPR budget is
// 128/wave and hoisting kf[4][2] (32 regs) forced scratch spill (round 8:
// WRITE_SIZE 16->88 MB). LDS = 40960 B -> exactly 4 blocks/CU; grid 1024.
// No-max softmax (|s/8| <~ 6, fp32-safe), Q pre-scaled so p = exp2(z).
// 2 barriers/iter; Pt rows wave-private.
// ---------------------------------------------------------------------------
__global__ __launch_bounds__(256, 4) void attn_kernel(const u16* __restrict__ Q,
                                                      const u16* __restrict__ K,
                                                      const u16* __restrict__ VT_g,
                                                      u16* __restrict__ O) {
    int g = blockIdx.y;
    int qtile = blockIdx.x;   // 0..31
    const u16* Qg = Q + (size_t)g * 262144;
    const u16* Kg = K + (size_t)g * 65536;
    const u16* Vt = VT_g + (size_t)g * 65536;   // [d][m], pitch 1024
    u16* Og = O + (size_t)g * 262144;

    __shared__ __align__(16) u16 Kt[128 * 64];    // XOR-8 swizzled [m][d]
    __shared__ __align__(16) u16 VTs[64 * 128];   // XOR-16 swizzled [d][m]
    __shared__ __align__(16) u16 Pt[64 * 64];     // XOR-4dw swizzled [n][m-half]

    int tid = threadIdx.x, lane = tid & 63, wave = tid >> 6;
    int q = lane >> 4, l16 = lane & 15;
    int n0 = qtile * 128;
    int pkey = (l16 & 7) << 2;            // dword-XOR key for Pt
    int prow = (wave * 16 + l16) * 32;    // Pt row base (dwords)
    int* Pt32 = (int*)Pt;

    bf16x8 qf[2][2];
#pragma unroll
    for (int s = 0; s < 2; ++s)
#pragma unroll
        for (int ds = 0; ds < 2; ++ds)
            qf[s][ds] = *(const bf16x8*)(
                &Qg[(size_t)(n0 + s * 64 + wave * 16 + l16) * 64 + ds * 32 + q * 8]);

    f32x4 oacc[2][4] = {};
    float rsum[2] = {0.f, 0.f};

    for (int kb = 0; kb < 8; ++kb) {
        __syncthreads();
#pragma unroll
        for (int t = 0; t < 4; ++t) {
            int c = wave * 64 + lane + t * 256;       // slot 0..1023
            {   // K tile: 128 m-rows x 64 d, XOR-8
                int m = c >> 3, kc = (c & 7) ^ (m & 7);
                gl2lds16(&Kg[(size_t)(kb * 128 + m) * 64 + kc * 8], &Kt[c * 8]);
            }
            {   // V^T tile: 64 d-rows x 128 m, XOR-16
                int d = c >> 4, mc = (c & 15) ^ (d & 15);
                gl2lds16(&Vt[(size_t)d * 1024 + kb * 128 + mc * 8], &VTs[c * 8]);
            }
        }
        __syncthreads();

#pragma unroll
        for (int h = 0; h < 2; ++h) {
#pragma unroll
            for (int s = 0; s < 2; ++s) {
                // S^T block; p = exp2(z); packed b64 write to Pt[n][m]
#pragma unroll
                for (int cb = 0; cb < 4; ++cb) {
                    int m = h * 64 + cb * 16 + l16;
                    bf16x8 kf0 = *(bf16x8*)(&Kt[m * 64 + ((q ^ (m & 7)) << 3)]);
                    bf16x8 kf1 = *(bf16x8*)(&Kt[m * 64 + (((4 + q) ^ (m & 7)) << 3)]);
                    f32x4 z = {};
                    z = __builtin_amdgcn_mfma_f32_16x16x32_bf16(kf0, qf[s][0], z, 0, 0, 0);
                    z = __builtin_amdgcn_mfma_f32_16x16x32_bf16(kf1, qf[s][1], z, 0, 0, 0);
                    float p0 = exp2f(z[0]), p1 = exp2f(z[1]);
                    float p2 = exp2f(z[2]), p3 = exp2f(z[3]);
                    rsum[s] += (p0 + p1) + (p2 + p3);
                    unsigned a0, a1, a2, a3;
                    __builtin_memcpy(&a0, &p0, 4); __builtin_memcpy(&a1, &p1, 4);
                    __builtin_memcpy(&a2, &p2, 4); __builtin_memcpy(&a3, &p3, 4);
                    int2 w;
                    w.x = (int)((a0 >> 16) | (a1 & 0xffff0000u));
                    w.y = (int)((a2 >> 16) | (a3 & 0xffff0000u));
                    int pd = (cb * 8 + q * 2) ^ pkey;
                    *(int2*)(&Pt32[prow + pd]) = w;
                }
                // O += P V (same wave wrote Pt rows; DS in-order, no barrier)
#pragma unroll
                for (int ds = 0; ds < 2; ++ds) {
                    int pd = (ds * 16 + q * 4) ^ pkey;
                    bf16x8 ap = *(bf16x8*)(&Pt32[prow + pd]);
#pragma unroll
                    for (int db = 0; db < 4; ++db) {
                        int dd = db * 16 + l16;
                        int jj = h * 8 + ds * 4 + q;
                        bf16x8 vb = *(bf16x8*)(&VTs[dd * 128 + ((jj ^ (dd & 15)) << 3)]);
                        oacc[s][db] = __builtin_amdgcn_mfma_f32_16x16x32_bf16(ap, vb, oacc[s][db], 0, 0, 0);
                    }
                }
            }
        }
    }

    // epilogue: rsum lives at row n=l16 (partial over quads) -> reduce over
    // quads, then fetch row (q*4+r)'s total via shfl, normalize, store.
#pragma unroll
    for (int s = 0; s < 2; ++s) {
        float v = rsum[s];
        v += __shfl_xor(v, 16, 64);
        v += __shfl_xor(v, 32, 64);
        rsum[s] = v;
    }
    float inv[2][4];
#pragma unroll
    for (int s = 0; s < 2; ++s)
#pragma unroll
        for (int r = 0; r < 4; ++r)
            inv[s][r] = 1.f / __shfl(rsum[s], q * 4 + r, 64);
#pragma unroll
    for (int s = 0; s < 2; ++s)
#pragma unroll
        for (int db = 0; db < 4; ++db)
#pragma unroll
            for (int r = 0; r < 4; ++r) {
                int row = n0 + s * 64 + wave * 16 + q * 4 + r;
                Og[(size_t)row * 64 + db * 16 + l16] = f2b(oacc[s][db][r] * inv[s][r]);
            }
}

// ---------------------------------------------------------------------------
extern "C" void kernel_launch(void* const* d_in, const int* in_sizes, int n_in,
                              void* d_out, int out_size, void* d_ws, size_t ws_size,
                              hipStream_t stream) {
    const float* x   = (const float*)d_in[0];
    const float* w_q = (const float*)d_in[1];
    const float* b_q = (const float*)d_in[2];
    const float* w_k = (const float*)d_in[3];
    const float* b_k = (const float*)d_in[4];
    const float* w_v = (const float*)d_in[5];
    const float* b_v = (const float*)d_in[6];
    const float* w_o = (const float*)d_in[7];
    const float* b_o = (const float*)d_in[8];
    float* out = (float*)d_out;

    char* ws = (char*)d_ws;
    u16* xb  = (u16*)(ws);                        // 16 MB (16384,512) bf16
    u16* xp  = (u16*)(ws + (16ull << 20));        //  4 MB (4096,512)
    u16* Qw  = (u16*)(ws + (20ull << 20));        // 16 MB (16384,512)
    u16* Kw  = (u16*)(ws + (36ull << 20));        //  4 MB (4096,512)
    u16* VwT = (u16*)(ws + (40ull << 20));        //  4 MB 32x(64,1024)
    u16* wT  = (u16*)(ws + (44ull << 20));        //  2 MB: 4 x 512x512 bf16
    u16* Ow  = xb;  // alias: xb's last reader (Q-GEMM) precedes attn's write

    cvt_kernel<<<8192, 256, 0, stream>>>(x, xb);
    wtrans_kernel<<<dim3(8, 8, 4), 256, 0, stream>>>(w_q, w_k, w_v, w_o, wT);
    pool_kernel<<<1024, 256, 0, stream>>>(xb, xp);
    // Q projection (scaled by log2(e)/8)
    gemm_bf16<0><<<dim3(4, 128), 256, 0, stream>>>(xb, wT, b_q, nullptr, Qw, nullptr, QSCALE);
    // fused K|V projection (N=1024 over adjacent K^T,V^T weights)
    gemm_bf16<3><<<dim3(8, 32), 256, 0, stream>>>(xp, wT + 262144, b_k, b_v, Kw, VwT, 1.0f);
    // attention: 32 q-tiles x 32 groups
    attn_kernel<<<dim3(32, 32), 256, 0, stream>>>(Qw, Kw, VwT, Ow);
    // output projection + f32 residual
    gemm_bf16<1><<<dim3(4, 128), 256, 0, stream>>>(Ow, wT + 786432, b_o, x, out, nullptr, 1.0f);
}